// Round 12
// baseline (794.719 us; speedup 1.0000x reference)
//
#include <hip/hip_runtime.h>

// QuantizedLinear: out[m][n] = 0.01 * sum_k x[m][k]*(q[n][k]-8) + (0.01*0.047)*qbias[n]
// M=16384, N=4096, K=4096.
// R12: B removed from LDS — B fragments loaded global->register direct from L2
// (lane pattern = 16 fully-used 64B lines per load), prefetched 1 tile ahead,
// parity double-buffered (2-tile unroll, static indexing). A stays gload_lds
// (ring of 4, 128 KiB), zero-conflict XOR swizzle (R3-verified). R6 free-slip
// schedule: 4 phases, 1 barrier/tile, counted lgkmcnt(4)/vmcnt(4), setprio,
// flipped XCD swizzle. LDS read demand/CU drops 2304->1536 cyc < MFMA 2065.

typedef __bf16 bf16x8 __attribute__((ext_vector_type(8)));
typedef float f32x4 __attribute__((ext_vector_type(4)));
typedef unsigned short u16;
typedef u16 u16x4 __attribute__((ext_vector_type(4)));
typedef u16 u16x8 __attribute__((ext_vector_type(8)));

static constexpr int Kdim = 4096;
static constexpr int Ndim = 4096;
static constexpr int BM = 256, BN = 256, BK = 64;
static constexpr int NKT = Kdim / BK;          // 64 K-tiles
static constexpr int TBUF = BM * BK;           // 16384 halfwords = 32 KiB per A buffer

__device__ __forceinline__ u16 f2bf(float f) {
  union { float f; unsigned u; } c; c.f = f;
  unsigned u = c.u;
  return (u16)((u + 0x7FFFu + ((u >> 16) & 1u)) >> 16);  // RNE
}

// ---- pre-pass 1: x fp32 -> bf16 ----
__global__ __launch_bounds__(256) void cvt_x_kernel(const float* __restrict__ x,
                                                    u16* __restrict__ xb, int n4) {
  int stride = gridDim.x * blockDim.x;
  for (int i = blockIdx.x * blockDim.x + threadIdx.x; i < n4; i += stride) {
    float4 v = reinterpret_cast<const float4*>(x)[i];
    u16x4 o;
    o.x = f2bf(v.x); o.y = f2bf(v.y); o.z = f2bf(v.z); o.w = f2bf(v.w);
    reinterpret_cast<u16x4*>(xb)[i] = o;
  }
}

// ---- pre-pass 2: packed nibbles -> bf16 integer weights (q-8), exact ----
__global__ __launch_bounds__(256) void dequant_w_kernel(const int* __restrict__ pw,
                                                        u16* __restrict__ wb, int n4) {
  int stride = gridDim.x * blockDim.x;
  for (int i = blockIdx.x * blockDim.x + threadIdx.x; i < n4; i += stride) {
    int4 v = reinterpret_cast<const int4*>(pw)[i];
    int a[4] = {v.x, v.y, v.z, v.w};
    u16x8 o;
#pragma unroll
    for (int j = 0; j < 4; ++j) {
      o[2 * j]     = f2bf((float)((a[j] & 15) - 8));
      o[2 * j + 1] = f2bf((float)(((a[j] >> 4) & 15) - 8));
    }
    reinterpret_cast<u16x8*>(wb)[i] = o;
  }
}

__device__ __forceinline__ void gload16(const u16* g, const u16* l) {
  __builtin_amdgcn_global_load_lds(
      (const __attribute__((address_space(1))) void*)g,
      (__attribute__((address_space(3))) void*)l,
      16, 0, 0);
}

// ---- main GEMM ----
__global__ __launch_bounds__(512, 2) void gemm_kernel(const u16* __restrict__ A,
                                                      const u16* __restrict__ B,
                                                      const int* __restrict__ qbias,
                                                      float* __restrict__ C,
                                                      int Ntiles) {
  extern __shared__ u16 smem[];
  u16* As = smem;                    // 4 x 256x64 = 128 KiB (A ring of 4)

  const int tid = threadIdx.x;
  const int lane = tid & 63;
  const int wave = tid >> 6;
  const int wm = wave >> 2, wn = wave & 3;   // 2 (M) x 4 (N) waves, each 128x64

  // Flipped XCD swizzle: bx fast within XCD chunk -> A panel L2-resident per XCD.
  const int cpx = gridDim.x >> 3;
  const int bid = blockIdx.x;
  const int swz = (bid & 7) * cpx + (bid >> 3);
  const int bx = swz % Ntiles;
  const int by = swz / Ntiles;
  const int m0 = by * BM, n0 = bx * BN;

  // ---- A staging geometry (source carries inverse of the read swizzle) ----
  const int srow = tid >> 3;
  const int fcol = (((tid & 7) ^ (srow & 7)) << 3);  // halfword col offset
  const u16* pa[4];
#pragma unroll
  for (int i = 0; i < 4; ++i)
    pa[i] = A + (size_t)(m0 + i * 64 + srow) * Kdim + fcol;
  const u16* pblane = B + (size_t)(n0 + wn * 64 + (lane & 15)) * Kdim + ((lane >> 4) * 8);
  const int wbase = (tid & 0x1C0) * 8;   // wave-uniform LDS halfword base (HW adds lane*16B)

  // ---- A ds_read geometry: phys slot = s_log ^ (row&7); row&7 == lane&7 ----
  const int e0 = ((lane >> 4) ^ (lane & 7)) << 3;    // k-half 0 slot offset (halfwords)
  const int e1 = e0 ^ 32;                            // k-half 1
  const int arow = (wm * 128 + (lane & 15)) * 64;    // A halfword row base

  f32x4 acc[8][4] = {};
  bf16x8 bq0[4][2], bq1[4][2];   // B frags, parity double-buffered (static idx)

  // ---- prologue: B(0)->bq0 (8 reg loads), A(0)->buf0, A(1)->buf1 ----
#pragma unroll
  for (int n = 0; n < 4; ++n) {
    bq0[n][0] = *(const bf16x8*)(pblane + (size_t)n * 16 * Kdim);
    bq0[n][1] = *(const bf16x8*)(pblane + (size_t)n * 16 * Kdim + 32);
  }
#pragma unroll
  for (int i = 0; i < 4; ++i) gload16(pa[i], As + i * 4096 + wbase);
#pragma unroll
  for (int i = 0; i < 4; ++i) gload16(pa[i] + BK, As + TBUF + i * 4096 + wbase);
  asm volatile("s_waitcnt vmcnt(4)" ::: "memory");   // B(0)+A(0) done; A(1) in flight
  __builtin_amdgcn_s_barrier();

#define MFMAS(ACC_BASE, AF, BQ, KH)                                           \
    asm volatile("s_waitcnt lgkmcnt(4)" ::: "memory");                        \
    __builtin_amdgcn_sched_barrier(0);                                        \
    __builtin_amdgcn_s_setprio(1);                                            \
    _Pragma("unroll")                                                         \
    for (int m = 0; m < 4; ++m)                                               \
      _Pragma("unroll")                                                       \
      for (int n = 0; n < 4; ++n)                                             \
        acc[(ACC_BASE) + m][n] = __builtin_amdgcn_mfma_f32_16x16x32_bf16(     \
            AF[m], BQ[n][KH], acc[(ACC_BASE) + m][n], 0, 0, 0);               \
    __builtin_amdgcn_s_setprio(0);

#define MFMAS0(ACC_BASE, AF, BQ, KH)                                          \
    asm volatile("s_waitcnt lgkmcnt(0)" ::: "memory");                        \
    __builtin_amdgcn_sched_barrier(0);                                        \
    __builtin_amdgcn_s_setprio(1);                                            \
    _Pragma("unroll")                                                         \
    for (int m = 0; m < 4; ++m)                                               \
      _Pragma("unroll")                                                       \
      for (int n = 0; n < 4; ++n)                                             \
        acc[(ACC_BASE) + m][n] = __builtin_amdgcn_mfma_f32_16x16x32_bf16(     \
            AF[m], BQ[n][KH], acc[(ACC_BASE) + m][n], 0, 0, 0);               \
    __builtin_amdgcn_s_setprio(0);

#define TILE(T, BQ_CUR, BQ_NXT)                                               \
  {                                                                           \
    const int t = (T);                                                        \
    const u16* aL = As + (t & 3) * TBUF;                                      \
    const u16* aW = As + ((t + 2) & 3) * TBUF;                                \
    const bool stb = (t + 1) < NKT;                                           \
    const bool sta = (t + 2) < NKT;                                           \
    const int kob = (t + 1) * BK;                                             \
    const int koa = (t + 2) * BK;                                             \
    bf16x8 a0[4], a1[4];                                                      \
    _Pragma("unroll")                                                         \
    for (int m = 0; m < 4; ++m)                                               \
      a0[m] = *(const bf16x8*)(aL + arow + m * 1024 + e0);                    \
    /* P0: read a1(mh1,kh0); load B(t+1) kh0; MFMA mh0-kh0 */                 \
    _Pragma("unroll")                                                         \
    for (int m = 0; m < 4; ++m)                                               \
      a1[m] = *(const bf16x8*)(aL + arow + 4096 + m * 1024 + e0);             \
    if (stb) {                                                                \
      _Pragma("unroll")                                                       \
      for (int n = 0; n < 4; ++n)                                             \
        BQ_NXT[n][0] = *(const bf16x8*)(pblane + (size_t)n * 16 * Kdim + kob);\
    }                                                                         \
    MFMAS(0, a0, BQ_CUR, 0)                                                   \
    /* P1: read a0'(mh0,kh1); load B(t+1) kh1; MFMA mh1-kh0 */                \
    _Pragma("unroll")                                                         \
    for (int m = 0; m < 4; ++m)                                               \
      a0[m] = *(const bf16x8*)(aL + arow + m * 1024 + e1);                    \
    if (stb) {                                                                \
      _Pragma("unroll")                                                       \
      for (int n = 0; n < 4; ++n)                                             \
        BQ_NXT[n][1] = *(const bf16x8*)(pblane + (size_t)n * 16 * Kdim + kob + 32);\
    }                                                                         \
    MFMAS(4, a1, BQ_CUR, 0)                                                   \
    /* P2: read a1'(mh1,kh1); stage A(t+2) x2; MFMA mh0-kh1 */                \
    _Pragma("unroll")                                                         \
    for (int m = 0; m < 4; ++m)                                               \
      a1[m] = *(const bf16x8*)(aL + arow + 4096 + m * 1024 + e1);             \
    if (sta) { gload16(pa[0] + koa, aW + 0 * 4096 + wbase);                   \
               gload16(pa[1] + koa, aW + 1 * 4096 + wbase); }                 \
    MFMAS(0, a0, BQ_CUR, 1)                                                   \
    /* P3: stage A(t+2) x2; MFMA mh1-kh1 */                                   \
    if (sta) { gload16(pa[2] + koa, aW + 2 * 4096 + wbase);                   \
               gload16(pa[3] + koa, aW + 3 * 4096 + wbase); }                 \
    MFMAS0(4, a1, BQ_CUR, 1)                                                  \
    __builtin_amdgcn_sched_barrier(0);                                        \
    /* boundary: B(t+1) regs + A(t+1) LDS landed; A(t+2) stays in flight */   \
    if (sta)      { asm volatile("s_waitcnt vmcnt(4)" ::: "memory"); }        \
    else if (stb) { asm volatile("s_waitcnt vmcnt(0)" ::: "memory"); }        \
    __builtin_amdgcn_s_barrier();                                             \
  }

  for (int j = 0; j < NKT / 2; ++j) {
    TILE(2 * j,     bq0, bq1)
    TILE(2 * j + 1, bq1, bq0)
  }
#undef TILE
#undef MFMAS
#undef MFMAS0

  // epilogue: C/D layout col=lane&15, row=(lane>>4)*4+j
  const float wscale = 0.01f;
  const float bscale = (float)(0.01 * 0.047);
  const int col0 = n0 + wn * 64 + (lane & 15);
  const int row0 = m0 + wm * 128 + ((lane >> 4) << 2);
#pragma unroll
  for (int n = 0; n < 4; ++n) {
    const int col = col0 + n * 16;
    const float bias = bscale * (float)qbias[col];
#pragma unroll
    for (int m = 0; m < 8; ++m) {
      const int rr = row0 + m * 16;
#pragma unroll
      for (int j = 0; j < 4; ++j)
        C[(size_t)(rr + j) * Ndim + col] = wscale * acc[m][n][j] + bias;
    }
  }
}

extern "C" void kernel_launch(void* const* d_in, const int* in_sizes, int n_in,
                              void* d_out, int out_size, void* d_ws, size_t ws_size,
                              hipStream_t stream) {
  const float* x  = (const float*)d_in[0];
  const int*   pw = (const int*)d_in[1];
  const int*   qb = (const int*)d_in[2];
  float* out = (float*)d_out;

  const int M = in_sizes[0] / Kdim;  // 16384

  u16* xb = (u16*)d_ws;                                  // M*K bf16
  u16* wb = (u16*)((char*)d_ws + (size_t)M * Kdim * 2);  // N*K bf16

  cvt_x_kernel<<<2048, 256, 0, stream>>>(x, xb, M * Kdim / 4);
  dequant_w_kernel<<<1024, 256, 0, stream>>>(pw, wb, Ndim * Kdim / 8);

  const int Ntiles = Ndim / BN;                  // 16
  const int nwg = (M / BM) * Ntiles;             // 1024, multiple of 8
  static const size_t lds_bytes = 4u * TBUF * sizeof(u16);  // 128 KiB (A only)
  (void)hipFuncSetAttribute((const void*)gemm_kernel,
                            hipFuncAttributeMaxDynamicSharedMemorySize,
                            (int)lds_bytes);
  gemm_kernel<<<nwg, 512, lds_bytes, stream>>>(xb, wb, qb, out, Ntiles);
}

// Round 13
// 734.597 us; speedup vs baseline: 1.0818x; 1.0818x over previous
//
#include <hip/hip_runtime.h>

// QuantizedLinear: out[m][n] = 0.01 * sum_k x[m][k]*(q[n][k]-8) + (0.01*0.047)*qbias[n]
// M=16384, N=4096, K=4096.
// R13 = R12 (B in registers, A-only LDS) with the register budget fixed:
// SINGLE-copy bq[4][2] (32 VGPRs, was 64 double-buffered -> spill at 256 cap).
// Per-wave program-order prefetch: P2 loads B(t+1)kh0 (bq[][0] dead after P1),
// P3 runs MFMA kh1 THEN loads B(t+1)kh1 (WAR: bq[][1] dead only after P3 MFMA)
// + 4x A(t+2) gload_lds. Waits: P2 vmcnt(8) retires k1B(t); boundary vmcnt(8)
// retires k0B(t+1)+A(t+1). A ring-of-4 LDS (128 KiB), zero-conflict XOR swizzle,
// flipped XCD swizzle, setprio, 1 barrier/tile.

typedef __bf16 bf16x8 __attribute__((ext_vector_type(8)));
typedef float f32x4 __attribute__((ext_vector_type(4)));
typedef unsigned short u16;
typedef u16 u16x4 __attribute__((ext_vector_type(4)));
typedef u16 u16x8 __attribute__((ext_vector_type(8)));

static constexpr int Kdim = 4096;
static constexpr int Ndim = 4096;
static constexpr int BM = 256, BN = 256, BK = 64;
static constexpr int NKT = Kdim / BK;          // 64 K-tiles
static constexpr int TBUF = BM * BK;           // 16384 halfwords = 32 KiB per A buffer

__device__ __forceinline__ u16 f2bf(float f) {
  union { float f; unsigned u; } c; c.f = f;
  unsigned u = c.u;
  return (u16)((u + 0x7FFFu + ((u >> 16) & 1u)) >> 16);  // RNE
}

// ---- pre-pass 1: x fp32 -> bf16 ----
__global__ __launch_bounds__(256) void cvt_x_kernel(const float* __restrict__ x,
                                                    u16* __restrict__ xb, int n4) {
  int stride = gridDim.x * blockDim.x;
  for (int i = blockIdx.x * blockDim.x + threadIdx.x; i < n4; i += stride) {
    float4 v = reinterpret_cast<const float4*>(x)[i];
    u16x4 o;
    o.x = f2bf(v.x); o.y = f2bf(v.y); o.z = f2bf(v.z); o.w = f2bf(v.w);
    reinterpret_cast<u16x4*>(xb)[i] = o;
  }
}

// ---- pre-pass 2: packed nibbles -> bf16 integer weights (q-8), exact ----
__global__ __launch_bounds__(256) void dequant_w_kernel(const int* __restrict__ pw,
                                                        u16* __restrict__ wb, int n4) {
  int stride = gridDim.x * blockDim.x;
  for (int i = blockIdx.x * blockDim.x + threadIdx.x; i < n4; i += stride) {
    int4 v = reinterpret_cast<const int4*>(pw)[i];
    int a[4] = {v.x, v.y, v.z, v.w};
    u16x8 o;
#pragma unroll
    for (int j = 0; j < 4; ++j) {
      o[2 * j]     = f2bf((float)((a[j] & 15) - 8));
      o[2 * j + 1] = f2bf((float)(((a[j] >> 4) & 15) - 8));
    }
    reinterpret_cast<u16x8*>(wb)[i] = o;
  }
}

__device__ __forceinline__ void gload16(const u16* g, const u16* l) {
  __builtin_amdgcn_global_load_lds(
      (const __attribute__((address_space(1))) void*)g,
      (__attribute__((address_space(3))) void*)l,
      16, 0, 0);
}

// ---- main GEMM ----
__global__ __launch_bounds__(512, 2) void gemm_kernel(const u16* __restrict__ A,
                                                      const u16* __restrict__ B,
                                                      const int* __restrict__ qbias,
                                                      float* __restrict__ C,
                                                      int Ntiles) {
  extern __shared__ u16 smem[];
  u16* As = smem;                    // 4 x 256x64 = 128 KiB (A ring of 4)

  const int tid = threadIdx.x;
  const int lane = tid & 63;
  const int wave = tid >> 6;
  const int wm = wave >> 2, wn = wave & 3;   // 2 (M) x 4 (N) waves, each 128x64

  // Flipped XCD swizzle: bx fast within XCD chunk -> A panel L2-resident per XCD.
  const int cpx = gridDim.x >> 3;
  const int bid = blockIdx.x;
  const int swz = (bid & 7) * cpx + (bid >> 3);
  const int bx = swz % Ntiles;
  const int by = swz / Ntiles;
  const int m0 = by * BM, n0 = bx * BN;

  // ---- A staging geometry (source carries inverse of the read swizzle) ----
  const int srow = tid >> 3;
  const int fcol = (((tid & 7) ^ (srow & 7)) << 3);  // halfword col offset
  const u16* pa[4];
#pragma unroll
  for (int i = 0; i < 4; ++i)
    pa[i] = A + (size_t)(m0 + i * 64 + srow) * Kdim + fcol;
  // B lane address: row = n0+wn*64+n*16+(lane&15), k-chunk = (lane>>4)*8
  const u16* pblane = B + (size_t)(n0 + wn * 64 + (lane & 15)) * Kdim + ((lane >> 4) * 8);
  const int wbase = (tid & 0x1C0) * 8;   // wave-uniform LDS halfword base (HW adds lane*16B)

  // ---- A ds_read geometry: phys slot = s_log ^ (row&7); row&7 == lane&7 ----
  const int e0 = ((lane >> 4) ^ (lane & 7)) << 3;    // k-half 0 slot offset (halfwords)
  const int e1 = e0 ^ 32;                            // k-half 1
  const int arow = (wm * 128 + (lane & 15)) * 64;    // A halfword row base

  f32x4 acc[8][4] = {};
  bf16x8 bq[4][2];               // single-copy B frags (32 VGPRs)

  // ---- prologue: B(0) both kh (8 reg loads), A(0)->buf0, A(1)->buf1 ----
#pragma unroll
  for (int n = 0; n < 4; ++n) {
    bq[n][0] = *(const bf16x8*)(pblane + (size_t)n * 16 * Kdim);
    bq[n][1] = *(const bf16x8*)(pblane + (size_t)n * 16 * Kdim + 32);
  }
#pragma unroll
  for (int i = 0; i < 4; ++i) gload16(pa[i], As + i * 4096 + wbase);
#pragma unroll
  for (int i = 0; i < 4; ++i) gload16(pa[i] + BK, As + TBUF + i * 4096 + wbase);
  asm volatile("s_waitcnt vmcnt(4)" ::: "memory");   // B(0)+A(0) done; A(1) in flight
  __builtin_amdgcn_s_barrier();

#define MFMA16(ACC_BASE, AF, KH)                                              \
    __builtin_amdgcn_sched_barrier(0);                                        \
    __builtin_amdgcn_s_setprio(1);                                            \
    _Pragma("unroll")                                                         \
    for (int m = 0; m < 4; ++m)                                               \
      _Pragma("unroll")                                                       \
      for (int n = 0; n < 4; ++n)                                             \
        acc[(ACC_BASE) + m][n] = __builtin_amdgcn_mfma_f32_16x16x32_bf16(     \
            AF[m], bq[n][KH], acc[(ACC_BASE) + m][n], 0, 0, 0);               \
    __builtin_amdgcn_s_setprio(0);

  for (int t = 0; t < NKT; ++t) {
    const u16* aL = As + (t & 3) * TBUF;
    const u16* aW = As + ((t + 2) & 3) * TBUF;
    const bool stb = (t + 1) < NKT;
    const bool sta = (t + 2) < NKT;
    const int kob = (t + 1) * BK;
    const int koa = (t + 2) * BK;

    bf16x8 a0[4], a1[4];

    // ---- tile-start: a0 (mh0, kh0) ----
#pragma unroll
    for (int m = 0; m < 4; ++m)
      a0[m] = *(const bf16x8*)(aL + arow + m * 1024 + e0);

    // ---- P0: read a1 (mh1,kh0); MFMA mh0-kh0 ----
#pragma unroll
    for (int m = 0; m < 4; ++m)
      a1[m] = *(const bf16x8*)(aL + arow + 4096 + m * 1024 + e0);
    asm volatile("s_waitcnt lgkmcnt(4)" ::: "memory");
    MFMA16(0, a0, 0)

    // ---- P1: read a0' (mh0,kh1); MFMA mh1-kh0 [bq[][0] dead after this] ----
#pragma unroll
    for (int m = 0; m < 4; ++m)
      a0[m] = *(const bf16x8*)(aL + arow + m * 1024 + e1);
    asm volatile("s_waitcnt lgkmcnt(4)" ::: "memory");
    MFMA16(4, a1, 0)

    // ---- P2: read a1' (mh1,kh1); load B(t+1)kh0 -> bq[][0];
    //          vmcnt(8) retires k1B(t); MFMA mh0-kh1 ----
#pragma unroll
    for (int m = 0; m < 4; ++m)
      a1[m] = *(const bf16x8*)(aL + arow + 4096 + m * 1024 + e1);
    if (stb) {
#pragma unroll
      for (int n = 0; n < 4; ++n)
        bq[n][0] = *(const bf16x8*)(pblane + (size_t)n * 16 * Kdim + kob);
    }
    asm volatile("s_waitcnt vmcnt(8)" ::: "memory");
    asm volatile("s_waitcnt lgkmcnt(4)" ::: "memory");
    MFMA16(0, a0, 1)

    // ---- P3: MFMA mh1-kh1 [bq[][1] dead after]; THEN load B(t+1)kh1 + A(t+2) ----
    asm volatile("s_waitcnt lgkmcnt(0)" ::: "memory");
    MFMA16(4, a1, 1)
    __builtin_amdgcn_sched_barrier(0);
    if (stb) {
#pragma unroll
      for (int n = 0; n < 4; ++n)
        bq[n][1] = *(const bf16x8*)(pblane + (size_t)n * 16 * Kdim + kob + 32);
    }
    if (sta) {
      gload16(pa[0] + koa, aW + 0 * 4096 + wbase);
      gload16(pa[1] + koa, aW + 1 * 4096 + wbase);
      gload16(pa[2] + koa, aW + 2 * 4096 + wbase);
      gload16(pa[3] + koa, aW + 3 * 4096 + wbase);
    }
    __builtin_amdgcn_sched_barrier(0);

    // ---- boundary: retire k0B(t+1) + A(t+1); leave k1B(t+1)+A(t+2) in flight ----
    if (sta)      { asm volatile("s_waitcnt vmcnt(8)" ::: "memory"); }
    else if (stb) { asm volatile("s_waitcnt vmcnt(0)" ::: "memory"); }
    __builtin_amdgcn_s_barrier();
  }
#undef MFMA16

  // epilogue: C/D layout col=lane&15, row=(lane>>4)*4+j
  const float wscale = 0.01f;
  const float bscale = (float)(0.01 * 0.047);
  const int col0 = n0 + wn * 64 + (lane & 15);
  const int row0 = m0 + wm * 128 + ((lane >> 4) << 2);
#pragma unroll
  for (int n = 0; n < 4; ++n) {
    const int col = col0 + n * 16;
    const float bias = bscale * (float)qbias[col];
#pragma unroll
    for (int m = 0; m < 8; ++m) {
      const int rr = row0 + m * 16;
#pragma unroll
      for (int j = 0; j < 4; ++j)
        C[(size_t)(rr + j) * Ndim + col] = wscale * acc[m][n][j] + bias;
    }
  }
}

extern "C" void kernel_launch(void* const* d_in, const int* in_sizes, int n_in,
                              void* d_out, int out_size, void* d_ws, size_t ws_size,
                              hipStream_t stream) {
  const float* x  = (const float*)d_in[0];
  const int*   pw = (const int*)d_in[1];
  const int*   qb = (const int*)d_in[2];
  float* out = (float*)d_out;

  const int M = in_sizes[0] / Kdim;  // 16384

  u16* xb = (u16*)d_ws;                                  // M*K bf16
  u16* wb = (u16*)((char*)d_ws + (size_t)M * Kdim * 2);  // N*K bf16

  cvt_x_kernel<<<2048, 256, 0, stream>>>(x, xb, M * Kdim / 4);
  dequant_w_kernel<<<1024, 256, 0, stream>>>(pw, wb, Ndim * Kdim / 8);

  const int Ntiles = Ndim / BN;                  // 16
  const int nwg = (M / BM) * Ntiles;             // 1024, multiple of 8
  static const size_t lds_bytes = 4u * TBUF * sizeof(u16);  // 128 KiB (A only)
  (void)hipFuncSetAttribute((const void*)gemm_kernel,
                            hipFuncAttributeMaxDynamicSharedMemorySize,
                            (int)lds_bytes);
  gemm_kernel<<<nwg, 512, lds_bytes, stream>>>(xb, wb, qb, out, Ntiles);
}

// Round 14
// 650.145 us; speedup vs baseline: 1.2224x; 1.1299x over previous
//
#include <hip/hip_runtime.h>

// QuantizedLinear: out[m][n] = 0.01 * sum_k x[m][k]*(q[n][k]-8) + (0.01*0.047)*qbias[n]
// M=16384, N=4096, K=4096.
// R14: B-direct-to-register, third attempt with both failure modes fixed:
// (1) B pre-packed fragment-contiguous (dequant pre-pass writes packed layout;
//     each wave B-load = contiguous 1KB, streaming; kills 8KB-stride L2 aliasing),
// (2) B prefetch distance 2 tiles (issued P3-end of t, used at t+2; boundary
//     vmcnt(12) retires B(t+1)+A(t+1); never 0 mid-loop).
// A via gload_lds ring-4 (128 KiB), zero-conflict XOR swizzle, flipped XCD
// swizzle, 4-phase 1-barrier/tile, setprio. LDS demand/CU/tile 4608->3072 cyc.

typedef __bf16 bf16x8 __attribute__((ext_vector_type(8)));
typedef float f32x4 __attribute__((ext_vector_type(4)));
typedef unsigned short u16;
typedef u16 u16x4 __attribute__((ext_vector_type(4)));
typedef u16 u16x8 __attribute__((ext_vector_type(8)));

static constexpr int Kdim = 4096;
static constexpr int Ndim = 4096;
static constexpr int BM = 256, BN = 256, BK = 64;
static constexpr int NKT = Kdim / BK;          // 64 K-tiles
static constexpr int TBUF = BM * BK;           // 32 KiB per A buffer (halfwords)

__device__ __forceinline__ u16 f2bf(float f) {
  union { float f; unsigned u; } c; c.f = f;
  unsigned u = c.u;
  return (u16)((u + 0x7FFFu + ((u >> 16) & 1u)) >> 16);  // RNE
}

// ---- pre-pass 1: x fp32 -> bf16 ----
__global__ __launch_bounds__(256) void cvt_x_kernel(const float* __restrict__ x,
                                                    u16* __restrict__ xb, int n4) {
  int stride = gridDim.x * blockDim.x;
  for (int i = blockIdx.x * blockDim.x + threadIdx.x; i < n4; i += stride) {
    float4 v = reinterpret_cast<const float4*>(x)[i];
    u16x4 o;
    o.x = f2bf(v.x); o.y = f2bf(v.y); o.z = f2bf(v.z); o.w = f2bf(v.w);
    reinterpret_cast<u16x4*>(xb)[i] = o;
  }
}

// ---- pre-pass 2: packed nibbles -> bf16 weights in FRAGMENT-PACKED layout ----
// Output group g (one u16x8 = 8 weights): g = (((c*64 + t)*2 + kh)*4 + kc2)*16 + r
//   c = column-block (16 rows), t = K-tile, kh = k-half, kc2 = k-chunk quad, r = row in block.
// Weight row o = c*16+r, k0 = t*64 + kh*32 + kc2*8.  GEMM wave-load for (c,t,kh)
// is then base + lane*16B: lane l = rows c*16+(l&15), k-chunk (l>>4)*8  — contiguous 1KB.
__global__ __launch_bounds__(256) void dequant_w_packed_kernel(const int* __restrict__ pw,
                                                               u16* __restrict__ wp, int ng) {
  int stride = gridDim.x * blockDim.x;
  for (int g = blockIdx.x * blockDim.x + threadIdx.x; g < ng; g += stride) {
    const int r   = g & 15;
    const int kc2 = (g >> 4) & 3;
    const int kh  = (g >> 6) & 1;
    const int t   = (g >> 7) & 63;
    const int c   = g >> 13;
    const int o   = c * 16 + r;
    const int kw  = t * 32 + kh * 16 + kc2 * 4;     // int32 index within row (k0/2)
    int4 v = *reinterpret_cast<const int4*>(pw + (size_t)o * (Kdim / 2) + kw);
    int a[4] = {v.x, v.y, v.z, v.w};
    u16x8 out;
#pragma unroll
    for (int j = 0; j < 4; ++j) {
      out[2 * j]     = f2bf((float)((a[j] & 15) - 8));        // even k
      out[2 * j + 1] = f2bf((float)(((a[j] >> 4) & 15) - 8)); // odd k
    }
    reinterpret_cast<u16x8*>(wp)[g] = out;
  }
}

__device__ __forceinline__ void gload16(const u16* g, const u16* l) {
  __builtin_amdgcn_global_load_lds(
      (const __attribute__((address_space(1))) void*)g,
      (__attribute__((address_space(3))) void*)l,
      16, 0, 0);
}

// ---- main GEMM: A via LDS (swizzled), B via packed global->register ----
__global__ __launch_bounds__(512, 2) void gemm_kernel(const u16* __restrict__ A,
                                                      const u16* __restrict__ Bp,
                                                      const int* __restrict__ qbias,
                                                      float* __restrict__ C,
                                                      int Ntiles) {
  extern __shared__ u16 smem[];
  u16* As = smem;                    // 4 x 256x64 = 128 KiB (A ring of 4)

  const int tid = threadIdx.x;
  const int lane = tid & 63;
  const int wave = tid >> 6;
  const int wm = wave >> 2, wn = wave & 3;   // 2 (M) x 4 (N) waves, each 128x64

  // Flipped XCD swizzle: bx fast within XCD chunk -> A panel L2-resident per XCD.
  const int cpx = gridDim.x >> 3;
  const int bid = blockIdx.x;
  const int swz = (bid & 7) * cpx + (bid >> 3);
  const int bx = swz % Ntiles;
  const int by = swz / Ntiles;
  const int m0 = by * BM, n0 = bx * BN;

  // ---- A staging geometry (source carries inverse of the read swizzle) ----
  const int srow = tid >> 3;
  const int fcol = (((tid & 7) ^ (srow & 7)) << 3);
  const u16* pa[4];
#pragma unroll
  for (int i = 0; i < 4; ++i)
    pa[i] = A + (size_t)(m0 + i * 64 + srow) * Kdim + fcol;
  const int wbase = (tid & 0x1C0) * 8;

  // ---- packed-B geometry: block (c,t,kh) at halfword off ((c*64+t)*2+kh)*512;
  //      per-lane +lane*8. c = n0/16 + wn*4 + nt; nt stride = 65536 halfwords. ----
  const u16* pbl = Bp + ((size_t)(n0 >> 4) + wn * 4) * 65536 + lane * 8;

  // ---- A ds_read geometry: phys slot = s_log ^ (row&7) ----
  const int e0 = ((lane >> 4) ^ (lane & 7)) << 3;
  const int e1 = e0 ^ 32;
  const int arow = (wm * 128 + (lane & 15)) * 64;

  f32x4 acc[8][4] = {};
  bf16x8 bqA[4][2], bqB[4][2];   // B frags for even/odd tiles (64 VGPRs)

  // ---- prologue: B(0)->bqA [8], A(0) gload [4], B(1)->bqB [8], A(1) gload [4] ----
#pragma unroll
  for (int n = 0; n < 4; ++n) {
    bqA[n][0] = *(const bf16x8*)(pbl + n * 65536 + 0 * 1024 + 0 * 512);
    bqA[n][1] = *(const bf16x8*)(pbl + n * 65536 + 0 * 1024 + 1 * 512);
  }
#pragma unroll
  for (int i = 0; i < 4; ++i) gload16(pa[i], As + i * 4096 + wbase);
#pragma unroll
  for (int n = 0; n < 4; ++n) {
    bqB[n][0] = *(const bf16x8*)(pbl + n * 65536 + 1 * 1024 + 0 * 512);
    bqB[n][1] = *(const bf16x8*)(pbl + n * 65536 + 1 * 1024 + 1 * 512);
  }
#pragma unroll
  for (int i = 0; i < 4; ++i) gload16(pa[i] + BK, As + TBUF + i * 4096 + wbase);
  asm volatile("s_waitcnt vmcnt(12)" ::: "memory");  // B(0)+A(0) done; B(1)+A(1) in flight
  __builtin_amdgcn_s_barrier();

#define MFMA16(ACC_BASE, AF, BQ, KH)                                          \
    __builtin_amdgcn_sched_barrier(0);                                        \
    __builtin_amdgcn_s_setprio(1);                                            \
    _Pragma("unroll")                                                         \
    for (int m = 0; m < 4; ++m)                                               \
      _Pragma("unroll")                                                       \
      for (int n = 0; n < 4; ++n)                                             \
        acc[(ACC_BASE) + m][n] = __builtin_amdgcn_mfma_f32_16x16x32_bf16(     \
            AF[m], BQ[n][KH], acc[(ACC_BASE) + m][n], 0, 0, 0);               \
    __builtin_amdgcn_s_setprio(0);

#define TILE(T, BQ)                                                           \
  {                                                                           \
    const int t = (T);                                                        \
    const u16* aL = As + (t & 3) * TBUF;                                      \
    const u16* aW = As + ((t + 2) & 3) * TBUF;                                \
    const bool st = (t + 2) < NKT;                                            \
    const int koa = (t + 2) * BK;                                             \
    bf16x8 a0[4], a1[4];                                                      \
    _Pragma("unroll")                                                         \
    for (int m = 0; m < 4; ++m)                                               \
      a0[m] = *(const bf16x8*)(aL + arow + m * 1024 + e0);                    \
    /* P0: read a1 (mh1,kh0); MFMA mh0-kh0 */                                 \
    _Pragma("unroll")                                                         \
    for (int m = 0; m < 4; ++m)                                               \
      a1[m] = *(const bf16x8*)(aL + arow + 4096 + m * 1024 + e0);             \
    asm volatile("s_waitcnt lgkmcnt(4)" ::: "memory");                        \
    MFMA16(0, a0, BQ, 0)                                                      \
    /* P1: read a0' (mh0,kh1); MFMA mh1-kh0 */                                \
    _Pragma("unroll")                                                         \
    for (int m = 0; m < 4; ++m)                                               \
      a0[m] = *(const bf16x8*)(aL + arow + m * 1024 + e1);                    \
    asm volatile("s_waitcnt lgkmcnt(4)" ::: "memory");                        \
    MFMA16(4, a1, BQ, 0)                                                      \
    /* P2: read a1' (mh1,kh1); MFMA mh0-kh1 */                                \
    _Pragma("unroll")                                                         \
    for (int m = 0; m < 4; ++m)                                               \
      a1[m] = *(const bf16x8*)(aL + arow + 4096 + m * 1024 + e1);             \
    asm volatile("s_waitcnt lgkmcnt(4)" ::: "memory");                        \
    MFMA16(0, a0, BQ, 1)                                                      \
    /* P3: MFMA mh1-kh1; THEN issue B(t+2)->BQ (dead) + A(t+2) gloads */      \
    asm volatile("s_waitcnt lgkmcnt(0)" ::: "memory");                        \
    MFMA16(4, a1, BQ, 1)                                                      \
    __builtin_amdgcn_sched_barrier(0);                                        \
    if (st) {                                                                 \
      _Pragma("unroll")                                                       \
      for (int n = 0; n < 4; ++n) {                                           \
        BQ[n][0] = *(const bf16x8*)(pbl + n * 65536 + (t + 2) * 1024);        \
        BQ[n][1] = *(const bf16x8*)(pbl + n * 65536 + (t + 2) * 1024 + 512);  \
      }                                                                       \
      gload16(pa[0] + koa, aW + 0 * 4096 + wbase);                            \
      gload16(pa[1] + koa, aW + 1 * 4096 + wbase);                            \
      gload16(pa[2] + koa, aW + 2 * 4096 + wbase);                            \
      gload16(pa[3] + koa, aW + 3 * 4096 + wbase);                            \
    }                                                                         \
    __builtin_amdgcn_sched_barrier(0);                                        \
    /* boundary: retire B(t+1)+A(t+1) (oldest 12); leave B(t+2)+A(t+2) */     \
    if (st)                { asm volatile("s_waitcnt vmcnt(12)" ::: "memory"); } \
    else if ((t + 1) < NKT){ asm volatile("s_waitcnt vmcnt(0)" ::: "memory"); }  \
    __builtin_amdgcn_s_barrier();                                             \
  }

  for (int j = 0; j < NKT / 2; ++j) {
    TILE(2 * j,     bqA)
    TILE(2 * j + 1, bqB)
  }
#undef TILE
#undef MFMA16

  // epilogue: C/D layout col=lane&15, row=(lane>>4)*4+j
  const float wscale = 0.01f;
  const float bscale = (float)(0.01 * 0.047);
  const int col0 = n0 + wn * 64 + (lane & 15);
  const int row0 = m0 + wm * 128 + ((lane >> 4) << 2);
#pragma unroll
  for (int n = 0; n < 4; ++n) {
    const int col = col0 + n * 16;
    const float bias = bscale * (float)qbias[col];
#pragma unroll
    for (int m = 0; m < 8; ++m) {
      const int rr = row0 + m * 16;
#pragma unroll
      for (int j = 0; j < 4; ++j)
        C[(size_t)(rr + j) * Ndim + col] = wscale * acc[m][n][j] + bias;
    }
  }
}

extern "C" void kernel_launch(void* const* d_in, const int* in_sizes, int n_in,
                              void* d_out, int out_size, void* d_ws, size_t ws_size,
                              hipStream_t stream) {
  const float* x  = (const float*)d_in[0];
  const int*   pw = (const int*)d_in[1];
  const int*   qb = (const int*)d_in[2];
  float* out = (float*)d_out;

  const int M = in_sizes[0] / Kdim;  // 16384

  u16* xb = (u16*)d_ws;                                  // M*K bf16 (134 MB)
  u16* wp = (u16*)((char*)d_ws + (size_t)M * Kdim * 2);  // packed B (33.5 MB)

  cvt_x_kernel<<<2048, 256, 0, stream>>>(x, xb, M * Kdim / 4);
  dequant_w_packed_kernel<<<2048, 256, 0, stream>>>(pw, wp, Ndim * Kdim / 8);

  const int Ntiles = Ndim / BN;                  // 16
  const int nwg = (M / BM) * Ntiles;             // 1024, multiple of 8
  static const size_t lds_bytes = 4u * TBUF * sizeof(u16);  // 128 KiB (A only)
  (void)hipFuncSetAttribute((const void*)gemm_kernel,
                            hipFuncAttributeMaxDynamicSharedMemorySize,
                            (int)lds_bytes);
  gemm_kernel<<<nwg, 512, lds_bytes, stream>>>(xb, wp, qb, out, Ntiles);
}